// Round 7
// baseline (355.461 us; speedup 1.0000x reference)
//
#include <hip/hip_runtime.h>

#define NN 100000
#define NE 1600000

#define BSH 9                                  // 512 nodes/bucket
#define NBUCK2 ((NN + 511) / 512)              // 196 coarse buckets
#define CHUNK 8192                             // edges per partition block
#define NCHK ((NE + CHUNK - 1) / CHUNK)        // 196 chunks
#define L2T (NBUCK2 * NCHK)                    // 38416
#define NSTRIP (NN / 32)                       // 3125 exact

using bf16x8 = __attribute__((ext_vector_type(8))) short;
using f32x16 = __attribute__((ext_vector_type(16))) float;

// ---- bf16 helpers (RNE) ----
__device__ __forceinline__ unsigned short f2bf(float f) {
    unsigned u = __float_as_uint(f);
    u += 0x7FFFu + ((u >> 16) & 1u);
    return (unsigned short)(u >> 16);
}
__device__ __forceinline__ float bf2f(unsigned short h) {
    return __uint_as_float(((unsigned)h) << 16);
}

// ---------------- per-chunk bucket histogram (LDS only) ----------------
__global__ __launch_bounds__(256) void hist2_kernel(const int* __restrict__ dst,
                                                    int* __restrict__ histm) {
    __shared__ int lh[256];
    int blk = blockIdx.x, tid = threadIdx.x;
    lh[tid] = 0;
    __syncthreads();
    int base = blk * CHUNK;
#pragma unroll
    for (int t = 0; t < CHUNK / 256; t++) {
        int e = base + t * 256 + tid;
        if (e < NE) atomicAdd(&lh[dst[e] >> BSH], 1);
    }
    __syncthreads();
    if (tid < NBUCK2) histm[tid * NCHK + blk] = lh[tid];   // bucket-major
}

// ---------------- single-block exclusive scan over histm (L2T ints) ----------------
// Replaces scan1+scan2+scan_add (3 dispatches). 1024 threads, each owns a
// contiguous span; two global passes + one 1024-wide Hillis-Steele in LDS.
__global__ __launch_bounds__(1024) void scan_histm_kernel(int* __restrict__ data) {
    __shared__ int s[1024];
    const int PER = (L2T + 1023) / 1024;        // 38
    int tid = threadIdx.x;
    int lo = tid * PER;
    int hi = lo + PER; if (hi > L2T) hi = L2T;
    int sum = 0;
    for (int i = lo; i < hi; i++) sum += data[i];
    s[tid] = sum;
    __syncthreads();
    for (int off = 1; off < 1024; off <<= 1) {
        int val = (tid >= off) ? s[tid - off] : 0;
        __syncthreads();
        s[tid] += val;
        __syncthreads();
    }
    int run = s[tid] - sum;                     // exclusive prefix of this span
    for (int i = lo; i < hi; i++) {
        int d = data[i];
        data[i] = run;
        run += d;
    }
}

// ---------------- deterministic coarse scatter (LDS cursors) ----------------
__global__ __launch_bounds__(256) void scatter2_kernel(const int* __restrict__ src,
                                                       const int* __restrict__ dst,
                                                       const int* __restrict__ histm,
                                                       int* __restrict__ tmp) {
    __shared__ int lcur[256];
    int blk = blockIdx.x, tid = threadIdx.x;
    if (tid < NBUCK2) lcur[tid] = histm[tid * NCHK + blk];
    __syncthreads();
    int base = blk * CHUNK;
#pragma unroll
    for (int t = 0; t < CHUNK / 256; t++) {
        int e = base + t * 256 + tid;
        if (e < NE) {
            int d = dst[e];
            int p = atomicAdd(&lcur[d >> BSH], 1);      // LDS atomic
            tmp[p] = src[e] | ((d & 511) << 17);        // src<2^17
        }
    }
}

// ---------------- fused count + scan + place per bucket ----------------
__global__ __launch_bounds__(256) void count_place_kernel(const int* __restrict__ histm,
                                                          const int* __restrict__ tmp,
                                                          int* __restrict__ rowptr,
                                                          int* __restrict__ esrc) {
    __shared__ int cnt[512];   // counts, then cursors
    __shared__ int s[256];
    int b = blockIdx.x, tid = threadIdx.x;
    int beg = histm[b * NCHK];
    int end = (b == NBUCK2 - 1) ? NE : histm[(b + 1) * NCHK];

    cnt[tid] = 0; cnt[tid + 256] = 0;
    __syncthreads();
    for (int e = beg + tid; e < end; e += 256)
        atomicAdd(&cnt[tmp[e] >> 17], 1);               // LDS atomic
    __syncthreads();

    int c0 = cnt[2 * tid], c1 = cnt[2 * tid + 1];
    int sum = c0 + c1;
    s[tid] = sum;
    __syncthreads();
    for (int off = 1; off < 256; off <<= 1) {
        int val = (tid >= off) ? s[tid - off] : 0;
        __syncthreads();
        s[tid] += val;
        __syncthreads();
    }
    int o0 = beg + s[tid] - sum;                        // exclusive
    int o1 = o0 + c0;
    cnt[2 * tid] = o0;                                  // cursors
    cnt[2 * tid + 1] = o1;
    int node0 = (b << BSH) + 2 * tid;
    if (node0 < NN)     rowptr[node0]     = o0;
    if (node0 + 1 < NN) rowptr[node0 + 1] = o1;
    if (b == 0 && tid == 0) rowptr[NN] = NE;
    __syncthreads();

    for (int e = beg + tid; e < end; e += 256) {
        int v = tmp[e];
        int p = atomicAdd(&cnt[v >> 17], 1);            // LDS atomic
        esrc[p] = v & 0x1FFFF;
    }
}

// ---------------- fp32 -> bf16 convert ----------------
__global__ __launch_bounds__(256) void cvt_kernel(const float* __restrict__ in,
                                                  unsigned short* __restrict__ out, int n4) {
    int i = blockIdx.x * 256 + threadIdx.x;
    if (i < n4) {
        float4 f = ((const float4*)in)[i];
        ((ushort4*)out)[i] = make_ushort4(f2bf(f.x), f2bf(f.y), f2bf(f.z), f2bf(f.w));
    }
}

// ---------------- all 4 weight planes in one dispatch ----------------
__global__ __launch_bounds__(256) void cvtw_kernel(const float* __restrict__ W1l,
                                                   const float* __restrict__ W1r,
                                                   const float* __restrict__ W2l,
                                                   const float* __restrict__ W2r,
                                                   unsigned short* __restrict__ W1lb,
                                                   unsigned short* __restrict__ W1rb,
                                                   unsigned short* __restrict__ W2lb,
                                                   unsigned short* __restrict__ W2rb) {
    const int N1 = 128 * 64 / 4, N2 = 128 * 128 / 4;
    int j = blockIdx.x * 256 + threadIdx.x;
    const float* in; unsigned short* out;
    if (j < N1)              { in = W1l; out = W1lb; }
    else if ((j -= N1) < N1) { in = W1r; out = W1rb; }
    else if ((j -= N1) < N2) { in = W2l; out = W2lb; }
    else                     { j -= N2; if (j >= N2) return; in = W2r; out = W2rb; }
    float4 f = ((const float4*)in)[j];
    ((ushort4*)out)[j] = make_ushort4(f2bf(f.x), f2bf(f.y), f2bf(f.z), f2bf(f.w));
}

// ---------------- fused mean-aggregate + MFMA GEMM ----------------
// One block = one 32-node strip. Phase A: wave w aggregates nodes w*8..w*8+7
// into LDS rows (exact agg64/agg128 loop structure/numerics, bf16 store ->
// identical rounding to the split version). LDS slot-XOR swizzle
// (slot ^= row & (K/8-1)) kills the row-major G4 bank conflict on phase-B
// ds_read_b128. Phase B: wave w computes output cols w*32..w*32+31
// (16 MFMAs: 8 for A1=LDS, 8 for A2=global row-major). Cross-block phase
// overlap hides GEMM under gather. launch_bounds(256,6): VGPR<=85 keeps
// gather occupancy ~24 waves/CU.
template <int K, bool RELU, bool OUTBF>
__global__ __launch_bounds__(256, 6) void agg_gemm_kernel(
    const unsigned short* __restrict__ feat,   // gather table [NN][K]
    const unsigned short* __restrict__ A2,     // self rows    [NN][K]
    const int* __restrict__ rowptr,
    const int* __restrict__ esrc,
    const unsigned short* __restrict__ Wa,     // [128][K]
    const unsigned short* __restrict__ Wb,     // [128][K]
    const float* __restrict__ bias,
    void* __restrict__ outv) {
    constexpr int SM = K / 8 - 1;              // LDS slot mask (16B slots/row - 1)
    __shared__ unsigned short As[32 * K];
    const int tid = threadIdx.x;
    const int w = tid >> 6;
    const int lane = tid & 63;
    const int base = blockIdx.x * 32;

    // ---- phase A ----
    if (K == 128) {
        int es = lane >> 4;            // edge slot 0..3
        int fi = lane & 15;            // 8-col block
        for (int ii = 0; ii < 8; ii++) {
            int row = w * 8 + ii;
            int node = base + row;
            int beg = rowptr[node], end = rowptr[node + 1];
            float ax[8];
#pragma unroll
            for (int i = 0; i < 8; i++) ax[i] = 0.0f;
            int e = beg;
            for (; e + 15 < end; e += 16) {
                int s0 = esrc[e + es];
                int s1 = esrc[e + 4 + es];
                int s2 = esrc[e + 8 + es];
                int s3 = esrc[e + 12 + es];
                bf16x8 u0 = *(const bf16x8*)(feat + (size_t)s0 * 128 + fi * 8);
                bf16x8 u1 = *(const bf16x8*)(feat + (size_t)s1 * 128 + fi * 8);
                bf16x8 u2 = *(const bf16x8*)(feat + (size_t)s2 * 128 + fi * 8);
                bf16x8 u3 = *(const bf16x8*)(feat + (size_t)s3 * 128 + fi * 8);
#pragma unroll
                for (int i = 0; i < 8; i++)
                    ax[i] += (bf2f((unsigned short)u0[i]) + bf2f((unsigned short)u1[i])) +
                             (bf2f((unsigned short)u2[i]) + bf2f((unsigned short)u3[i]));
            }
            for (; e + 3 < end; e += 4) {
                int s = esrc[e + es];
                bf16x8 u = *(const bf16x8*)(feat + (size_t)s * 128 + fi * 8);
#pragma unroll
                for (int i = 0; i < 8; i++) ax[i] += bf2f((unsigned short)u[i]);
            }
            if (es < end - e) {
                int s = esrc[e + es];
                bf16x8 u = *(const bf16x8*)(feat + (size_t)s * 128 + fi * 8);
#pragma unroll
                for (int i = 0; i < 8; i++) ax[i] += bf2f((unsigned short)u[i]);
            }
#pragma unroll
            for (int i = 0; i < 8; i++) {
                ax[i] += __shfl_xor(ax[i], 16);
                ax[i] += __shfl_xor(ax[i], 32);
            }
            if (es == 0) {
                float inv = 1.0f / fmaxf((float)(end - beg), 1.0f);
                bf16x8 o;
#pragma unroll
                for (int i = 0; i < 8; i++) o[i] = (short)f2bf(ax[i] * inv);
                *(bf16x8*)(As + row * K + ((fi ^ (row & SM)) * 8)) = o;
            }
        }
    } else {  // K == 64
        int es = lane >> 3;            // edge slot 0..7
        int fi = lane & 7;             // 8-col block
        for (int ii = 0; ii < 8; ii++) {
            int row = w * 8 + ii;
            int node = base + row;
            int beg = rowptr[node], end = rowptr[node + 1];
            float ax[8];
#pragma unroll
            for (int i = 0; i < 8; i++) ax[i] = 0.0f;
            int e = beg;
            for (; e + 15 < end; e += 16) {
                int sA = esrc[e + es];
                int sB = esrc[e + 8 + es];
                bf16x8 uA = *(const bf16x8*)(feat + (size_t)sA * 64 + fi * 8);
                bf16x8 uB = *(const bf16x8*)(feat + (size_t)sB * 64 + fi * 8);
#pragma unroll
                for (int i = 0; i < 8; i++)
                    ax[i] += bf2f((unsigned short)uA[i]) + bf2f((unsigned short)uB[i]);
            }
            if (e + 7 < end) {
                int s = esrc[e + es];
                bf16x8 u = *(const bf16x8*)(feat + (size_t)s * 64 + fi * 8);
#pragma unroll
                for (int i = 0; i < 8; i++) ax[i] += bf2f((unsigned short)u[i]);
                e += 8;
            }
            if (es < end - e) {
                int s = esrc[e + es];
                bf16x8 u = *(const bf16x8*)(feat + (size_t)s * 64 + fi * 8);
#pragma unroll
                for (int i = 0; i < 8; i++) ax[i] += bf2f((unsigned short)u[i]);
            }
#pragma unroll
            for (int i = 0; i < 8; i++) {
                ax[i] += __shfl_xor(ax[i], 8);
                ax[i] += __shfl_xor(ax[i], 16);
                ax[i] += __shfl_xor(ax[i], 32);
            }
            if (es == 0) {
                float inv = 1.0f / fmaxf((float)(end - beg), 1.0f);
                bf16x8 o;
#pragma unroll
                for (int i = 0; i < 8; i++) o[i] = (short)f2bf(ax[i] * inv);
                *(bf16x8*)(As + row * K + ((fi ^ (row & SM)) * 8)) = o;
            }
        }
    }
    __syncthreads();

    // ---- phase B: wave w -> output cols w*32..w*32+31 ----
    const int m = lane & 31;
    const int half = lane >> 5;
    f32x16 acc;
#pragma unroll
    for (int r = 0; r < 16; ++r) acc[r] = 0.0f;

#pragma unroll
    for (int kc = 0; kc < K; kc += 16) {
        int slot = (kc >> 3) + half;
        bf16x8 a = *(const bf16x8*)(As + m * K + ((slot ^ (m & SM)) * 8));
        bf16x8 b = *(const bf16x8*)(Wa + (size_t)(w * 32 + m) * K + kc + half * 8);
        acc = __builtin_amdgcn_mfma_f32_32x32x16_bf16(a, b, acc, 0, 0, 0);
    }
    const unsigned short* ar2 = A2 + (size_t)(base + m) * K + half * 8;
#pragma unroll
    for (int kc = 0; kc < K; kc += 16) {
        bf16x8 a = *(const bf16x8*)(ar2 + kc);
        bf16x8 b = *(const bf16x8*)(Wb + (size_t)(w * 32 + m) * K + kc + half * 8);
        acc = __builtin_amdgcn_mfma_f32_32x32x16_bf16(a, b, acc, 0, 0, 0);
    }

    int j = w * 32 + m;
    float bz = bias[j];
#pragma unroll
    for (int r = 0; r < 16; ++r) {
        int row = (r & 3) + 8 * (r >> 2) + 4 * half;
        float v = acc[r] + bz;
        if (RELU) v = fmaxf(v, 0.0f);
        size_t idx = (size_t)(base + row) * 128 + j;
        if (OUTBF) ((unsigned short*)outv)[idx] = f2bf(v);
        else       ((float*)outv)[idx] = v;
    }
}

extern "C" void kernel_launch(void* const* d_in, const int* in_sizes, int n_in,
                              void* d_out, int out_size, void* d_ws, size_t ws_size,
                              hipStream_t stream) {
    const float* x   = (const float*)d_in[0];
    const int*   ei  = (const int*)d_in[1];
    const float* W1l = (const float*)d_in[2];
    const float* W1r = (const float*)d_in[3];
    const float* b1  = (const float*)d_in[4];
    const float* W2l = (const float*)d_in[5];
    const float* W2r = (const float*)d_in[6];
    const float* b2  = (const float*)d_in[7];
    float* out = (float*)d_out;

    const int* src = ei;        // edge_index[0]
    const int* dst = ei + NE;   // edge_index[1]

    // ---- workspace layout (58,003,456 B, proven available) ----
    // rowptr/esrc live through both fused layers. W2 bf16 planes sit in the
    // (now unused) old-aggB lower half. xb keeps its old address. E region:
    // tmp/histm transient during CSR build, then hb (25.6 MB) overwrites.
    // W1 bf16 planes live in d_out (written only by fused-L2 at the end).
    char* ws = (char*)d_ws;
    int* rowptr = (int*)ws;                                  // [0, 401408)
    int* esrc   = (int*)(ws + 401408);                       // NE ints
    unsigned short* W2lb = (unsigned short*)(ws + 6803456);  // 128*128 bf16
    unsigned short* W2rb = W2lb + 128 * 128;                 // 128*128 bf16
    unsigned short* xb   = (unsigned short*)(ws + 19603456); // NN*64 bf16
    char* E = ws + 32403456;                                 // 25.6 MB region
    unsigned short* hb = (unsigned short*)E;                 // NN*128 bf16
    int* tmp   = (int*)E;                                    // NE ints (transient)
    int* histm = (int*)(E + 6400000);                        // L2T ints (transient)
    unsigned short* W1lb = (unsigned short*)d_out;           // 128*64 bf16
    unsigned short* W1rb = W1lb + 128 * 64;

    // ---- build CSR (edge list sorted by dst); no global atomics ----
    hist2_kernel<<<NCHK, 256, 0, stream>>>(dst, histm);
    scan_histm_kernel<<<1, 1024, 0, stream>>>(histm);
    scatter2_kernel<<<NCHK, 256, 0, stream>>>(src, dst, histm, tmp);
    count_place_kernel<<<NBUCK2, 256, 0, stream>>>(histm, tmp, rowptr, esrc);

    // ---- bf16 planes ----
    cvt_kernel<<<(NN * 64 / 4 + 255) / 256, 256, 0, stream>>>(x, xb, NN * 64 / 4);
    cvtw_kernel<<<48, 256, 0, stream>>>(W1l, W1r, W2l, W2r, W1lb, W1rb, W2lb, W2rb);

    // ---- layer 1 (fused): hb = bf16(relu(mean_agg(xb) @ W1l.T + xb @ W1r.T + b1)) ----
    agg_gemm_kernel<64, true, true><<<NSTRIP, 256, 0, stream>>>(
        xb, xb, rowptr, esrc, W1lb, W1rb, b1, hb);

    // ---- layer 2 (fused): out = mean_agg(hb) @ W2l.T + hb @ W2r.T + b2 ----
    agg_gemm_kernel<128, false, false><<<NSTRIP, 256, 0, stream>>>(
        hb, hb, rowptr, esrc, W2lb, W2rb, b2, out);
}